// Round 2
// baseline (265.751 us; speedup 1.0000x reference)
//
#include <hip/hip_runtime.h>

// LSTM B=8192, T=168, P=16, H=24, gates [i,f,g,o].
// Round-11: 2-wave blocks, 4 tiles/wave -> half-register h-exchange.
//  - r10 post-mortem: trans-count cut (20->14/wave) moved step only 36 cyc
//    (1472->1436): latency/sync-bound, not issue-bound. Chain = 4-wave
//    barrier + ds_read_b128 h + MFMA + act chain; bank conflicts 5.06M
//    (unpadded xs16: all 16 n-lanes same banks).
//  - Restructure: wave w owns tiles mt=4w..4w+3 -> lane (q,n) computes h of
//    units 8q+4w..8q+4w+3 == B1 dwords 2w,2w+1 for its own (q,n). Own half
//    of B1 never leaves registers; partner half = 2 ds_write_b32 +
//    2 ds_read_b32 at hxd[j][lane] (consecutive-lane -> conflict-free).
//    One TWO-wave __syncthreads per step. 512 blocks x 128 thr = 4 waves/CU
//    ~ 1/SIMD; 4 independent recurrence chains per CU.
//  - xs16 padded +24 f16/batch: per-step x ds_read_b128 16-way -> 2-way.
//  - Cell math identical to r10 (fused-denominator, 7 trans/cell).

#define T_STEPS 168
#define P_FEAT  16
#define TCH     84                 // t-chunk length (2 chunks)
#define NB      16                 // batches per block
#define BPAD    24                 // f16 pad per batch (2-way banks)
#define BSTR    (TCH * 16 + BPAD)  // 1368 f16 per batch

typedef _Float16 half8 __attribute__((ext_vector_type(8)));
typedef _Float16 h2    __attribute__((ext_vector_type(2)));
typedef float    f32x4 __attribute__((ext_vector_type(4)));
typedef unsigned uint4v __attribute__((ext_vector_type(4)));

__device__ __forceinline__ float rcp_fast(float x) {
#if __has_builtin(__builtin_amdgcn_rcpf)
    return __builtin_amdgcn_rcpf(x);
#else
    return 1.0f / x;
#endif
}
__device__ __forceinline__ float exp2_fast(float x) {
#if __has_builtin(__builtin_amdgcn_exp2f)
    return __builtin_amdgcn_exp2f(x);
#else
    return exp2f(x);
#endif
}
__device__ __forceinline__ float tanh_f(float x) {
    return 1.0f - 2.0f * rcp_fast(1.0f + exp2_fast(x * 2.88539008f));
}
__device__ __forceinline__ h2 pack2(float a, float b) {
    h2 r; r.x = (_Float16)a; r.y = (_Float16)b; return r;
}

__global__ __launch_bounds__(128, 1) void lstm_2w(
    const float* __restrict__ x,
    const float* __restrict__ W_ih,
    const float* __restrict__ W_hh,
    const float* __restrict__ b_ih,
    const float* __restrict__ b_hh,
    const float* __restrict__ W_lin,
    const float* __restrict__ b_lin,
    float* __restrict__ out)
{
    __shared__ __align__(16) _Float16 xs16[NB * BSTR];   // 43776 B (W-stage reused)
    __shared__ __align__(16) unsigned hxd[2][4][64];     //  2048 B [buf][dword j][lane]
    __shared__ __align__(16) _Float16 zblk[16];          //    32 B zeros (B2 pad)
    __shared__ __align__(16) float    thbuf[NB][24];     //  1536 B epilogue

    const int tid  = threadIdx.x;
    const int w    = tid >> 6;       // wave 0..1: tiles {4w..4w+3}
    const int lane = tid & 63;
    const int n    = lane & 15;      // batch col (B/C) == row p supplied (A)
    const int q    = lane >> 4;      // k-chunk (A/B) == output quad (C)

    // ---- one-time: stage fused W (f32) into xs16 space ----
    float* wstage = reinterpret_cast<float*>(xs16);      // 96*40 f32
    for (int idx = tid; idx < 96 * 40; idx += 128) {
        const int j = idx / 40;
        const int k = idx - j * 40;
        wstage[idx] = (k < 24) ? W_hh[j * 24 + k] : W_ih[j * 16 + (k - 24)];
    }
    __syncthreads();

    // ---- A-fragments for this wave's 4 tiles (mt = 4w+s) ----
    // tile row p: gate p%4 of unit 8*(p/4)+mt; rows p>=12 zero.
    // A-frag layout: A[m=lane&15][k=quad*8+j].
    half8 A1[4], A2[4];
    f32x4 biasf[4];
    #pragma unroll
    for (int s = 0; s < 4; s++) {
        const int mt = 4 * w + s;
        const int p  = n;
        const bool vrow = (p < 12);
        const int grow = vrow ? ((p & 3) * 24 + 8 * (p >> 2) + mt) : 0;
        #pragma unroll
        for (int j = 0; j < 8; j++) {
            const int k = q * 8 + j;
            A1[s][j] = (vrow && k < 24) ? (_Float16)wstage[grow * 40 + k]      : (_Float16)0.0f;
            A2[s][j] = (vrow && k < 16) ? (_Float16)wstage[grow * 40 + 24 + k] : (_Float16)0.0f;
        }
        #pragma unroll
        for (int r = 0; r < 4; r++) {
            const int u = 8 * q + mt;   // lane (q,n) holds gates r of unit u (q<3)
            biasf[s][r] = (q < 3) ? (b_ih[r * 24 + u] + b_hh[r * 24 + u]) : 0.0f;
        }
    }
    // zero hxd (both buffers; q=3 slots stay 0 forever) + zblk
    {
        unsigned* hz = &hxd[0][0][0];                    // 512 dwords
        for (int i = tid; i < 512; i += 128) hz[i] = 0u;
        if (tid < 8) reinterpret_cast<unsigned*>(zblk)[tid] = 0u;
    }
    __syncthreads();   // wstage dead; x staging reuses the space

    float c[4]  = {0.0f, 0.0f, 0.0f, 0.0f};
    float hv[4] = {0.0f, 0.0f, 0.0f, 0.0f};
    unsigned od0 = 0u, od1 = 0u;   // own B1 dwords (h of units 8q+4w+{0..3})

    const float4* xsrc = reinterpret_cast<const float4*>(x)
                       + (size_t)(blockIdx.x * NB) * (T_STEPS * P_FEAT / 4);

    // B2 source: quads 0..1 read x halves, quads 2..3 the zero block
    const _Float16* xrowbase = (q < 2) ? &xs16[n * BSTR + q * 8] : zblk;
    const int xstep = (q < 2) ? 16 : 0;

    const int pjj = w ? 0 : 2;     // partner's dword pair index

    int bufp = 0;
    for (int ch = 0; ch < 2; ch++) {
        // stage NB x TCH x 16 f32 -> f16 (padded layout): 5376 float4, 42/thread
        for (int i = 0; i < 42; i++) {
            const int m   = tid + 128 * i;      // 0..5375
            const int b   = m / 336;            // 336 float4 per batch-chunk
            const int rem = m - b * 336;
            const float4 v = xsrc[(size_t)b * 672 + ch * 336 + rem];
            h2* dst = reinterpret_cast<h2*>(xs16) + b * (BSTR / 2) + rem * 2;
            dst[0] = pack2(v.x, v.y);
            dst[1] = pack2(v.z, v.w);
        }
        __syncthreads();

        // gx prologue for t=0 of this chunk
        f32x4 gx[4];
        {
            const half8 B2 = *reinterpret_cast<const half8*>(xrowbase);
            #pragma unroll
            for (int s = 0; s < 4; s++)
                gx[s] = __builtin_amdgcn_mfma_f32_16x16x32_f16(A2[s], B2, biasf[s], 0, 0, 0);
        }

        for (int t = 0; t < TCH; t++) {
            // partner's half of B1 (conflict-free: addr = lane)
            const unsigned pd0 = hxd[bufp][pjj + 0][lane];
            const unsigned pd1 = hxd[bufp][pjj + 1][lane];
            // B1 dword j = units (8q+2j, 8q+2j+1); wave0 owns j=0,1; wave1 j=2,3
            uint4v bw;
            bw.x = w ? pd0 : od0;
            bw.y = w ? pd1 : od1;
            bw.z = w ? od0 : pd0;
            bw.w = w ? od1 : pd1;
            const half8 B1 = __builtin_bit_cast(half8, bw);

            // prefetch next step's x fragment (last iter: dummy index 0)
            const int tn = (t + 1 < TCH) ? t + 1 : 0;
            const half8 B2n = *reinterpret_cast<const half8*>(xrowbase + tn * xstep);

            f32x4 g[4];
            #pragma unroll
            for (int s = 0; s < 4; s++)
                g[s] = __builtin_amdgcn_mfma_f32_16x16x32_f16(A1[s], B1, gx[s], 0, 0, 0);
            #pragma unroll
            for (int s = 0; s < 4; s++)
                gx[s] = __builtin_amdgcn_mfma_f32_16x16x32_f16(A2[s], B2n, biasf[s], 0, 0, 0);

            // fused-denominator activations: 7 trans per cell, 4 cells
            #pragma unroll
            for (int s = 0; s < 4; s++) {
                const float Y  = exp2_fast(g[s][0] * -1.44269504f);  // i
                const float X  = exp2_fast(g[s][1] * -1.44269504f);  // f
                const float Z  = exp2_fast(g[s][2] *  2.88539008f);  // g
                const float V  = exp2_fast(g[s][3] * -1.44269504f);  // o
                const float ax = 1.0f + X;
                const float ay = 1.0f + Y;
                const float az = 1.0f + Z;
                const float num = c[s] * ay * az + ax * (Z - 1.0f);
                const float cn  = num * rcp_fast(ax * ay * az);
                c[s] = cn;
                const float W  = exp2_fast(fminf(cn, 18.0f) * 2.88539008f);
                hv[s] = (W - 1.0f) * rcp_fast((1.0f + V) * (1.0f + W));
            }

            // repack own dwords; publish to the other buffer (q=3: hv==0, skip)
            od0 = __builtin_bit_cast(unsigned, pack2(hv[0], hv[1]));
            od1 = __builtin_bit_cast(unsigned, pack2(hv[2], hv[3]));
            if (q < 3) {
                hxd[1 - bufp][2 * w + 0][lane] = od0;
                hxd[1 - bufp][2 * w + 1][lane] = od1;
            }
            bufp ^= 1;
            __syncthreads();
        }
    }

    // ---- epilogue: out[b][u] = b_lin[u] + sum_k tanh(h[k]) * W_lin[u][k] ----
    if (q < 3) {
        #pragma unroll
        for (int s = 0; s < 4; s++)
            thbuf[n][8 * q + 4 * w + s] = tanh_f(hv[s]);
    }
    __syncthreads();

    if (q < 3) {
        const int batch = blockIdx.x * NB + n;
        #pragma unroll
        for (int s = 0; s < 4; s++) {
            const int u = 8 * q + 4 * w + s;
            const float* wl = &W_lin[u * 24];
            float acc = b_lin[u];
            #pragma unroll
            for (int k = 0; k < 24; k++) acc = fmaf(thbuf[n][k], wl[k], acc);
            out[(size_t)batch * 24 + u] = acc;
        }
    }
}

extern "C" void kernel_launch(void* const* d_in, const int* in_sizes, int n_in,
                              void* d_out, int out_size, void* d_ws, size_t ws_size,
                              hipStream_t stream) {
    const float* x     = (const float*)d_in[0];
    const float* W_ih  = (const float*)d_in[1];
    const float* W_hh  = (const float*)d_in[2];
    const float* b_ih  = (const float*)d_in[3];
    const float* b_hh  = (const float*)d_in[4];
    const float* W_lin = (const float*)d_in[5];
    const float* b_lin = (const float*)d_in[6];
    float* out = (float*)d_out;

    const int B = in_sizes[0] / (T_STEPS * P_FEAT);   // 8192
    dim3 grid(B / NB), block(128);                    // 512 blocks x 2 waves
    lstm_2w<<<grid, block, 0, stream>>>(x, W_ih, W_hh, b_ih, b_hh, W_lin, b_lin, out);
}

// Round 3
// 195.945 us; speedup vs baseline: 1.3563x; 1.3563x over previous
//
#include <hip/hip_runtime.h>

// LSTM B=8192, T=168, P=16, H=24, gates [i,f,g,o].
// Round-12: 8 waves x 1 tile/wave -> 4 waves/SIMD latency hiding.
//  - r11 post-mortem: 2-wave/128-thr blocks halved occupancy to 1 wave/SIMD;
//    step ballooned 1436->2414 cyc (VALUBusy 32%): kernel is LATENCY-bound,
//    waves/SIMD is the dominant knob. r10 (2/SIMD) = 1436 cyc/step.
//  - This round: 512-thr blocks, 8 waves, wave w owns tile mt=w.
//    512 blocks x 8 waves = 2 blocks/CU = 16 waves/CU = 4 waves/SIMD.
//    Per-wave step work: 2 ds_read_b128 + 2 MFMA + 1 cell (7 trans) +
//    1 ds_write_b16. Self-aligned exchange: lane (q,n) of wave w computes
//    unit u=8q+w == element j=w of every lane's B1 half8 -> write
//    hx[q][n][w], read half8 hx[q][n][0..7]. No shuffles.
//  - xs16 keeps r11's +24 f16/batch pad (x-read 2-way banks).
//  - Cell math identical to r10/r11 (fused-denominator, 7 trans/cell).

#define T_STEPS 168
#define P_FEAT  16
#define TCH     84                 // t-chunk length (2 chunks)
#define NB      16                 // batches per block
#define BPAD    24                 // f16 pad per batch (2-way banks)
#define BSTR    (TCH * 16 + BPAD)  // 1368 f16 per batch

typedef _Float16 half8 __attribute__((ext_vector_type(8)));
typedef _Float16 h2    __attribute__((ext_vector_type(2)));
typedef float    f32x4 __attribute__((ext_vector_type(4)));

__device__ __forceinline__ float rcp_fast(float x) {
#if __has_builtin(__builtin_amdgcn_rcpf)
    return __builtin_amdgcn_rcpf(x);
#else
    return 1.0f / x;
#endif
}
__device__ __forceinline__ float exp2_fast(float x) {
#if __has_builtin(__builtin_amdgcn_exp2f)
    return __builtin_amdgcn_exp2f(x);
#else
    return exp2f(x);
#endif
}
__device__ __forceinline__ float tanh_f(float x) {
    return 1.0f - 2.0f * rcp_fast(1.0f + exp2_fast(x * 2.88539008f));
}
__device__ __forceinline__ h2 pack2(float a, float b) {
    h2 r; r.x = (_Float16)a; r.y = (_Float16)b; return r;
}

__global__ __launch_bounds__(512, 4) void lstm_8w(
    const float* __restrict__ x,
    const float* __restrict__ W_ih,
    const float* __restrict__ W_hh,
    const float* __restrict__ b_ih,
    const float* __restrict__ b_hh,
    const float* __restrict__ W_lin,
    const float* __restrict__ b_lin,
    float* __restrict__ out)
{
    __shared__ __align__(16) _Float16 xs16[NB * BSTR];     // 43776 B (W-stage reused)
    __shared__ __align__(16) _Float16 hx[2][4][NB][8];     //  2048 B ping-pong h
    __shared__ __align__(16) _Float16 zblk[16];            //    32 B zeros (B2 pad)
    __shared__ __align__(16) float    thbuf[NB][24];       //  1536 B epilogue

    const int tid  = threadIdx.x;
    const int w    = tid >> 6;       // wave 0..7: tile mt = w
    const int lane = tid & 63;
    const int n    = lane & 15;      // batch col (B/C) == row p supplied (A)
    const int q    = lane >> 4;      // k-chunk (A/B) == output quad (C)

    // ---- one-time: stage fused W (f32) into xs16 space ----
    float* wstage = reinterpret_cast<float*>(xs16);        // 96*40 f32
    for (int idx = tid; idx < 96 * 40; idx += 512) {
        const int j = idx / 40;
        const int k = idx - j * 40;
        wstage[idx] = (k < 24) ? W_hh[j * 24 + k] : W_ih[j * 16 + (k - 24)];
    }
    __syncthreads();

    // ---- A-fragments for this wave's tile (mt = w) ----
    // tile row p: gate p%4 of unit 8*(p/4)+mt; rows p>=12 zero.
    // A-frag layout: A[m=lane&15][k=quad*8+j].
    half8 A1, A2;
    f32x4 biasf;
    {
        const int mt = w;
        const int p  = n;
        const bool vrow = (p < 12);
        const int grow = vrow ? ((p & 3) * 24 + 8 * (p >> 2) + mt) : 0;
        #pragma unroll
        for (int j = 0; j < 8; j++) {
            const int k = q * 8 + j;
            A1[j] = (vrow && k < 24) ? (_Float16)wstage[grow * 40 + k]      : (_Float16)0.0f;
            A2[j] = (vrow && k < 16) ? (_Float16)wstage[grow * 40 + 24 + k] : (_Float16)0.0f;
        }
        #pragma unroll
        for (int r = 0; r < 4; r++) {
            const int u = 8 * q + mt;   // lane (q,n) holds gates r of unit u (q<3)
            biasf[r] = (q < 3) ? (b_ih[r * 24 + u] + b_hh[r * 24 + u]) : 0.0f;
        }
    }
    // zero hx (both buffers; q=3 rows stay 0 forever = k-pad) + zblk
    {
        unsigned* hz = reinterpret_cast<unsigned*>(&hx[0][0][0][0]);  // 512 dwords
        for (int i = tid; i < 512; i += 512) hz[i] = 0u;
        if (tid < 8) reinterpret_cast<unsigned*>(zblk)[tid] = 0u;
    }
    __syncthreads();   // wstage dead; x staging reuses the space

    float c  = 0.0f;
    float hv = 0.0f;

    const float4* xsrc = reinterpret_cast<const float4*>(x)
                       + (size_t)(blockIdx.x * NB) * (T_STEPS * P_FEAT / 4);

    // B2 source: quads 0..1 read x halves, quads 2..3 the zero block
    const _Float16* xrowbase = (q < 2) ? &xs16[n * BSTR + q * 8] : zblk;
    const int xstep = (q < 2) ? 16 : 0;

    int bufp = 0;
    for (int ch = 0; ch < 2; ch++) {
        // stage NB x TCH x 16 f32 -> f16 (padded layout): 5376 float4
        for (int i = 0; i < 11; i++) {
            const int m = tid + 512 * i;        // 0..5375
            if (m < 5376) {
                const int b   = m / 336;        // 336 float4 per batch-chunk
                const int rem = m - b * 336;
                const float4 v = xsrc[(size_t)b * 672 + ch * 336 + rem];
                h2* dst = reinterpret_cast<h2*>(xs16) + b * (BSTR / 2) + rem * 2;
                dst[0] = pack2(v.x, v.y);
                dst[1] = pack2(v.z, v.w);
            }
        }
        __syncthreads();

        // gx prologue for t=0 of this chunk
        f32x4 gx;
        {
            const half8 B2 = *reinterpret_cast<const half8*>(xrowbase);
            gx = __builtin_amdgcn_mfma_f32_16x16x32_f16(A2, B2, biasf, 0, 0, 0);
        }

        for (int t = 0; t < TCH; t++) {
            // B1: element j = h of unit 8q+j for batch n (j=w written by wave w)
            const half8 B1 = *reinterpret_cast<const half8*>(&hx[bufp][q][n][0]);
            // prefetch next step's x fragment (last iter: dummy index 0)
            const int tn = (t + 1 < TCH) ? t + 1 : 0;
            const half8 B2n = *reinterpret_cast<const half8*>(xrowbase + tn * xstep);

            f32x4 g = __builtin_amdgcn_mfma_f32_16x16x32_f16(A1, B1, gx, 0, 0, 0);
            gx = __builtin_amdgcn_mfma_f32_16x16x32_f16(A2, B2n, biasf, 0, 0, 0);

            // fused-denominator activations: 7 trans for this lane's cell
            //   c' = [c(1+Y)(1+Z) + (1+X)(Z-1)] * rcp((1+X)(1+Y)(1+Z))
            //   h  = (W-1) * rcp((1+V)(1+W)),  W = e^{2*min(c',18)}
            {
                const float Y  = exp2_fast(g[0] * -1.44269504f);  // i
                const float X  = exp2_fast(g[1] * -1.44269504f);  // f
                const float Z  = exp2_fast(g[2] *  2.88539008f);  // g
                const float V  = exp2_fast(g[3] * -1.44269504f);  // o
                const float ax = 1.0f + X;
                const float ay = 1.0f + Y;
                const float az = 1.0f + Z;
                const float num = c * ay * az + ax * (Z - 1.0f);
                const float cn  = num * rcp_fast(ax * ay * az);
                c = cn;
                const float W  = exp2_fast(fminf(cn, 18.0f) * 2.88539008f);
                hv = (W - 1.0f) * rcp_fast((1.0f + V) * (1.0f + W));
            }

            // publish own unit to the other buffer; q=3 stays zero (k-pad)
            if (q < 3) hx[1 - bufp][q][n][w] = (_Float16)hv;
            bufp ^= 1;
            __syncthreads();
        }
    }

    // ---- epilogue: out[b][u] = b_lin[u] + sum_k tanh(h[k]) * W_lin[u][k] ----
    if (q < 3) thbuf[n][8 * q + w] = tanh_f(hv);
    __syncthreads();

    if (q < 3) {
        const int batch = blockIdx.x * NB + n;
        const int u = 8 * q + w;
        const float* wl = &W_lin[u * 24];
        float acc = b_lin[u];
        #pragma unroll
        for (int k = 0; k < 24; k++) acc = fmaf(thbuf[n][k], wl[k], acc);
        out[(size_t)batch * 24 + u] = acc;
    }
}

extern "C" void kernel_launch(void* const* d_in, const int* in_sizes, int n_in,
                              void* d_out, int out_size, void* d_ws, size_t ws_size,
                              hipStream_t stream) {
    const float* x     = (const float*)d_in[0];
    const float* W_ih  = (const float*)d_in[1];
    const float* W_hh  = (const float*)d_in[2];
    const float* b_ih  = (const float*)d_in[3];
    const float* b_hh  = (const float*)d_in[4];
    const float* W_lin = (const float*)d_in[5];
    const float* b_lin = (const float*)d_in[6];
    float* out = (float*)d_out;

    const int B = in_sizes[0] / (T_STEPS * P_FEAT);   // 8192
    dim3 grid(B / NB), block(512);                    // 512 blocks x 8 waves
    lstm_8w<<<grid, block, 0, stream>>>(x, W_ih, W_hh, b_ih, b_hh, W_lin, b_lin, out);
}